// Round 4
// baseline (2646.542 us; speedup 1.0000x reference)
//
#include <hip/hip_runtime.h>
#include <hip/hip_bf16.h>

// GraphNetworkMetaLayer on MI355X (gfx950).
// Buffers are FP32 (per reference dtypes; the test's "bf16" refers to the
// demoted reference used for thresholding). edge_index int32.
// d_out layout (fp32): node_out [N,32] | edge_out [E,32] | global_out [32].
// f32 accumulators in module __device__ statics, zeroed each launch.
// Weights/activations demoted to bf16 in LDS (matches ref demotion, halves LDS).

#define NMAX 100000

__device__ float g_agg[NMAX * 32];   // 12.8 MB
__device__ float g_cnt[NMAX];        // 0.4 MB
__device__ float g_gsum[32];

static __device__ __forceinline__ float us2f(unsigned short u) {
  union { unsigned int u32; float f; } c;
  c.u32 = ((unsigned int)u) << 16;
  return c.f;
}
// fp32 -> bf16 raw bits, round-to-nearest-even (finite inputs).
static __device__ __forceinline__ unsigned short f2us(float f) {
  union { float f; unsigned int u; } c;
  c.f = f;
  const unsigned int r = 0x7FFFu + ((c.u >> 16) & 1u);
  return (unsigned short)((c.u + r) >> 16);
}

// ---------------- zero the accumulators (every call; statics persist) -------
__global__ __launch_bounds__(256) void zero_kernel() {
  const int i = blockIdx.x * 256 + threadIdx.x;
  if (i < NMAX * 32) g_agg[i] = 0.f;
  if (i < NMAX) g_cnt[i] = 0.f;
  if (i < 32) g_gsum[i] = 0.f;
}

// ---------------- edge model: MLP([x_src, x_dst, edge_attr, g]) ----------------
// 32 edges / block, 256 threads. Layer1: 128->128 (relu), layer2: 128->32.
__global__ __launch_bounds__(256) void edge_kernel(
    const float* __restrict__ x,
    const int* __restrict__ eidx,          // [2][E]: row then col
    const float* __restrict__ edge_attr,
    const float* __restrict__ gattr,
    const float* __restrict__ W1,   // [128][128]
    const float* __restrict__ b1,   // [128]
    const float* __restrict__ W2,   // [128][32]
    const float* __restrict__ b2,   // [32]
    float* __restrict__ edge_out,   // [E][32]
    const int E)
{
  __shared__ __align__(16) unsigned short s_in[32][128];   // 8 KB (bf16)
  __shared__ __align__(16) unsigned short s_h[32][136];    // 8.5 KB, padded rows
  __shared__ __align__(16) unsigned short s_W1[128 * 128]; // 32 KB
  __shared__ __align__(16) unsigned short s_W2[128 * 32];  // 8 KB
  __shared__ float s_b1[128];
  __shared__ float s_b2[32];
  __shared__ int s_src[32];
  __shared__ int s_dst[32];
  // total ~58.7 KB

  const int t = threadIdx.x;
  const int e0 = blockIdx.x * 32;

  // ---- stage weights (fp32 -> bf16) + biases + indices ----
  {
    const float4* w1s = (const float4*)W1;    // 4096 x float4
#pragma unroll
    for (int i = 0; i < 16; ++i) {
      const int idx = t + 256 * i;
      const float4 f = w1s[idx];
      ushort4 u; u.x = f2us(f.x); u.y = f2us(f.y); u.z = f2us(f.z); u.w = f2us(f.w);
      *(ushort4*)&s_W1[idx * 4] = u;
    }
    const float4* w2s = (const float4*)W2;    // 1024 x float4
#pragma unroll
    for (int i = 0; i < 4; ++i) {
      const int idx = t + 256 * i;
      const float4 f = w2s[idx];
      ushort4 u; u.x = f2us(f.x); u.y = f2us(f.y); u.z = f2us(f.z); u.w = f2us(f.w);
      *(ushort4*)&s_W2[idx * 4] = u;
    }
    if (t < 128) s_b1[t] = b1[t];
    else if (t >= 224) s_b2[t - 224] = b2[t - 224];
    if (t >= 128 && t < 160) {
      const int ge = e0 + (t - 128);
      s_src[t - 128] = (ge < E) ? eidx[ge] : 0;
      s_dst[t - 128] = (ge < E) ? eidx[(size_t)E + ge] : 0;
    }
  }
  __syncthreads();

  // ---- stage e_in = [x_src | x_dst | edge_attr | g] : 32 x 128 (bf16) ----
#pragma unroll
  for (int it = 0; it < 16; ++it) {
    const int i = t + it * 256;
    const int e = i >> 7, k = i & 127;
    const int ge = e0 + e;
    float v = 0.f;
    if (ge < E) {
      if (k < 32)      v = x[(size_t)s_src[e] * 32 + k];
      else if (k < 64) v = x[(size_t)s_dst[e] * 32 + (k - 32)];
      else if (k < 96) v = edge_attr[(size_t)ge * 32 + (k - 64)];
      else             v = gattr[k - 96];
    }
    s_in[e][k] = f2us(v);
  }
  __syncthreads();

  // ---- layer 1: 32x128 outputs, thread = 4e x 4j register tile ----
  {
    const int j0 = (t & 31) * 4;
    const int eb = (t >> 5) * 4;
    float acc[4][4];
#pragma unroll
    for (int i = 0; i < 4; ++i)
#pragma unroll
      for (int j = 0; j < 4; ++j) acc[i][j] = s_b1[j0 + j];
#pragma unroll 4
    for (int k = 0; k < 128; ++k) {
      const float a0 = us2f(s_in[eb + 0][k]);
      const float a1 = us2f(s_in[eb + 1][k]);
      const float a2 = us2f(s_in[eb + 2][k]);
      const float a3 = us2f(s_in[eb + 3][k]);
      const ushort4 w = *(const ushort4*)&s_W1[k * 128 + j0];
      const float w0 = us2f(w.x), w1v = us2f(w.y), w2v = us2f(w.z), w3v = us2f(w.w);
      acc[0][0] += a0 * w0; acc[0][1] += a0 * w1v; acc[0][2] += a0 * w2v; acc[0][3] += a0 * w3v;
      acc[1][0] += a1 * w0; acc[1][1] += a1 * w1v; acc[1][2] += a1 * w2v; acc[1][3] += a1 * w3v;
      acc[2][0] += a2 * w0; acc[2][1] += a2 * w1v; acc[2][2] += a2 * w2v; acc[2][3] += a2 * w3v;
      acc[3][0] += a3 * w0; acc[3][1] += a3 * w1v; acc[3][2] += a3 * w2v; acc[3][3] += a3 * w3v;
    }
#pragma unroll
    for (int i = 0; i < 4; ++i) {
      ushort4 r;
      r.x = f2us(fmaxf(acc[i][0], 0.f));
      r.y = f2us(fmaxf(acc[i][1], 0.f));
      r.z = f2us(fmaxf(acc[i][2], 0.f));
      r.w = f2us(fmaxf(acc[i][3], 0.f));
      *(ushort4*)&s_h[eb + i][j0] = r;
    }
  }
  __syncthreads();

  // ---- layer 2: 32x32 outputs, thread = (1e, 4f); write + scatter-add ----
  {
    const int e = t >> 3;
    const int f0 = (t & 7) * 4;
    float acc2[4] = { s_b2[f0 + 0], s_b2[f0 + 1], s_b2[f0 + 2], s_b2[f0 + 3] };
#pragma unroll 4
    for (int j = 0; j < 128; ++j) {
      const float hv = us2f(s_h[e][j]);
      const ushort4 w = *(const ushort4*)&s_W2[j * 32 + f0];
      acc2[0] += hv * us2f(w.x);
      acc2[1] += hv * us2f(w.y);
      acc2[2] += hv * us2f(w.z);
      acc2[3] += hv * us2f(w.w);
    }
    const int ge = e0 + e;
    if (ge < E) {
      float4 o = make_float4(acc2[0], acc2[1], acc2[2], acc2[3]);
      *(float4*)&edge_out[(size_t)ge * 32 + f0] = o;
      const int dst = s_dst[e];
      float* ap = g_agg + (size_t)dst * 32 + f0;
      atomicAdd(ap + 0, acc2[0]);
      atomicAdd(ap + 1, acc2[1]);
      atomicAdd(ap + 2, acc2[2]);
      atomicAdd(ap + 3, acc2[3]);
      if (f0 == 0) atomicAdd(&g_cnt[dst], 1.0f);
    }
  }
}

// ---------------- node model: MLP([x, agg, g]) + partial sums for mean ----------------
__global__ __launch_bounds__(256) void node_kernel(
    const float* __restrict__ x,
    const float* __restrict__ gattr,
    const float* __restrict__ W1,   // [96][128]
    const float* __restrict__ b1,   // [128]
    const float* __restrict__ W2,   // [128][32]
    const float* __restrict__ b2,   // [32]
    float* __restrict__ node_out,   // [N][32]
    const int N)
{
  __shared__ __align__(16) unsigned short s_in[32][104];   // 96 used, padded
  __shared__ __align__(16) unsigned short s_h[32][136];
  __shared__ __align__(16) unsigned short s_W1[96 * 128];  // 24 KB
  __shared__ __align__(16) unsigned short s_W2[128 * 32];  // 8 KB
  __shared__ float s_b1[128];
  __shared__ float s_b2[32];
  __shared__ float s_bsum[32];
  // total ~49 KB

  const int t = threadIdx.x;
  const int n0 = blockIdx.x * 32;

  {
    const float4* w1s = (const float4*)W1;    // 3072 x float4
#pragma unroll
    for (int i = 0; i < 12; ++i) {
      const int idx = t + 256 * i;
      const float4 f = w1s[idx];
      ushort4 u; u.x = f2us(f.x); u.y = f2us(f.y); u.z = f2us(f.z); u.w = f2us(f.w);
      *(ushort4*)&s_W1[idx * 4] = u;
    }
    const float4* w2s = (const float4*)W2;    // 1024 x float4
#pragma unroll
    for (int i = 0; i < 4; ++i) {
      const int idx = t + 256 * i;
      const float4 f = w2s[idx];
      ushort4 u; u.x = f2us(f.x); u.y = f2us(f.y); u.z = f2us(f.z); u.w = f2us(f.w);
      *(ushort4*)&s_W2[idx * 4] = u;
    }
    if (t < 128) s_b1[t] = b1[t];
    else if (t < 160) s_b2[t - 128] = b2[t - 128];
    else if (t < 192) s_bsum[t - 160] = 0.f;
  }

  // ---- stage n_in = [x | agg/max(cnt,1) | g] : 32 x 96 (bf16) ----
  {
    const int n = t >> 3;
    const int gn = n0 + n;
    const int kb = (t & 7) * 12;
    if (gn < N) {
      const float inv = 1.0f / fmaxf(g_cnt[gn], 1.0f);
#pragma unroll
      for (int kk = 0; kk < 12; ++kk) {
        const int k = kb + kk;
        float v;
        if (k < 32)      v = x[(size_t)gn * 32 + k];
        else if (k < 64) v = g_agg[(size_t)gn * 32 + (k - 32)] * inv;
        else             v = gattr[k - 64];
        s_in[n][k] = f2us(v);
      }
    } else {
#pragma unroll
      for (int kk = 0; kk < 12; ++kk) s_in[n][kb + kk] = 0;
    }
  }
  __syncthreads();

  // ---- layer 1: 32x128, thread = 4n x 4j ----
  {
    const int j0 = (t & 31) * 4;
    const int eb = (t >> 5) * 4;
    float acc[4][4];
#pragma unroll
    for (int i = 0; i < 4; ++i)
#pragma unroll
      for (int j = 0; j < 4; ++j) acc[i][j] = s_b1[j0 + j];
#pragma unroll 4
    for (int k = 0; k < 96; ++k) {
      const float a0 = us2f(s_in[eb + 0][k]);
      const float a1 = us2f(s_in[eb + 1][k]);
      const float a2 = us2f(s_in[eb + 2][k]);
      const float a3 = us2f(s_in[eb + 3][k]);
      const ushort4 w = *(const ushort4*)&s_W1[k * 128 + j0];
      const float w0 = us2f(w.x), w1v = us2f(w.y), w2v = us2f(w.z), w3v = us2f(w.w);
      acc[0][0] += a0 * w0; acc[0][1] += a0 * w1v; acc[0][2] += a0 * w2v; acc[0][3] += a0 * w3v;
      acc[1][0] += a1 * w0; acc[1][1] += a1 * w1v; acc[1][2] += a1 * w2v; acc[1][3] += a1 * w3v;
      acc[2][0] += a2 * w0; acc[2][1] += a2 * w1v; acc[2][2] += a2 * w2v; acc[2][3] += a2 * w3v;
      acc[3][0] += a3 * w0; acc[3][1] += a3 * w1v; acc[3][2] += a3 * w2v; acc[3][3] += a3 * w3v;
    }
#pragma unroll
    for (int i = 0; i < 4; ++i) {
      ushort4 r;
      r.x = f2us(fmaxf(acc[i][0], 0.f));
      r.y = f2us(fmaxf(acc[i][1], 0.f));
      r.z = f2us(fmaxf(acc[i][2], 0.f));
      r.w = f2us(fmaxf(acc[i][3], 0.f));
      *(ushort4*)&s_h[eb + i][j0] = r;
    }
  }
  __syncthreads();

  // ---- layer 2 + epilogue ----
  {
    const int n = t >> 3;
    const int f0 = (t & 7) * 4;
    float acc2[4] = { s_b2[f0 + 0], s_b2[f0 + 1], s_b2[f0 + 2], s_b2[f0 + 3] };
#pragma unroll 4
    for (int j = 0; j < 128; ++j) {
      const float hv = us2f(s_h[n][j]);
      const ushort4 w = *(const ushort4*)&s_W2[j * 32 + f0];
      acc2[0] += hv * us2f(w.x);
      acc2[1] += hv * us2f(w.y);
      acc2[2] += hv * us2f(w.z);
      acc2[3] += hv * us2f(w.w);
    }
    const int gn = n0 + n;
    if (gn < N) {
      float4 o = make_float4(acc2[0], acc2[1], acc2[2], acc2[3]);
      *(float4*)&node_out[(size_t)gn * 32 + f0] = o;
      atomicAdd(&s_bsum[f0 + 0], acc2[0]);
      atomicAdd(&s_bsum[f0 + 1], acc2[1]);
      atomicAdd(&s_bsum[f0 + 2], acc2[2]);
      atomicAdd(&s_bsum[f0 + 3], acc2[3]);
    }
  }
  __syncthreads();
  if (t < 32) atomicAdd(&g_gsum[t], s_bsum[t]);
}

// ---------------- global model: MLP([mean(node_out), g]) ----------------
__global__ __launch_bounds__(128) void global_kernel(
    const float* __restrict__ gattr,
    const float* __restrict__ W1,   // [64][128]
    const float* __restrict__ b1,   // [128]
    const float* __restrict__ W2,   // [128][32]
    const float* __restrict__ b2,   // [32]
    float* __restrict__ gout,       // [32]
    const int N)
{
  __shared__ float s_gin[64];
  __shared__ float s_h[128];
  const int t = threadIdx.x;
  if (t < 32) s_gin[t] = g_gsum[t] / (float)N;
  else if (t < 64) s_gin[t] = gattr[t - 32];
  __syncthreads();
  {
    float a = b1[t];
#pragma unroll 4
    for (int k = 0; k < 64; ++k) a += s_gin[k] * W1[k * 128 + t];
    s_h[t] = fmaxf(a, 0.f);
  }
  __syncthreads();
  if (t < 32) {
    float o = b2[t];
#pragma unroll 4
    for (int j = 0; j < 128; ++j) o += s_h[j] * W2[j * 32 + t];
    gout[t] = o;
  }
}

extern "C" void kernel_launch(void* const* d_in, const int* in_sizes, int n_in,
                              void* d_out, int out_size, void* d_ws, size_t ws_size,
                              hipStream_t stream)
{
  const float* x         = (const float*)d_in[0];
  const int*   eidx      = (const int*)d_in[1];
  const float* edge_attr = (const float*)d_in[2];
  const float* gattr     = (const float*)d_in[3];
  const float* W1e = (const float*)d_in[4];
  const float* b1e = (const float*)d_in[5];
  const float* W2e = (const float*)d_in[6];
  const float* b2e = (const float*)d_in[7];
  const float* W1n = (const float*)d_in[8];
  const float* b1n = (const float*)d_in[9];
  const float* W2n = (const float*)d_in[10];
  const float* b2n = (const float*)d_in[11];
  const float* W1g = (const float*)d_in[12];
  const float* b1g = (const float*)d_in[13];
  const float* W2g = (const float*)d_in[14];
  const float* b2g = (const float*)d_in[15];

  const int N = in_sizes[0] / 32;
  const int E = in_sizes[2] / 32;

  float* node_out = (float*)d_out;
  float* edge_out = node_out + (size_t)N * 32;
  float* gout     = edge_out + (size_t)E * 32;

  zero_kernel<<<dim3((NMAX * 32 + 255) / 256), dim3(256), 0, stream>>>();
  edge_kernel<<<dim3((E + 31) / 32), dim3(256), 0, stream>>>(
      x, eidx, edge_attr, gattr, W1e, b1e, W2e, b2e, edge_out, E);
  node_kernel<<<dim3((N + 31) / 32), dim3(256), 0, stream>>>(
      x, gattr, W1n, b1n, W2n, b2n, node_out, N);
  global_kernel<<<dim3(1), dim3(128), 0, stream>>>(
      gattr, W1g, b1g, W2g, b2g, gout, N);
}